// Round 24
// baseline (63.780 us; speedup 1.0000x reference)
//
#include <hip/hip_runtime.h>
#include <hip/hip_bf16.h>

// Problem constants
#define B_ 128
#define S_ 512
#define C_ 64
#define H_ 4
#define D_ 32
// SCALE * log2(e): folded into Wq/bq at prep so softmax uses raw exp2
#define QSCALE_LOG2E 0.25505654249765306f

typedef __attribute__((ext_vector_type(8))) short bf16x8;
typedef __attribute__((ext_vector_type(8))) unsigned short u16x8;
typedef __attribute__((ext_vector_type(4))) unsigned short u16x4;
typedef __attribute__((ext_vector_type(4))) float f32x4;
typedef __attribute__((ext_vector_type(4))) unsigned int u32x4;
typedef __attribute__((ext_vector_type(2))) unsigned int u32x2;

__device__ __forceinline__ unsigned short f2bf(float f) {
    unsigned int u = __float_as_uint(f);
    u = (u + 0x7FFFu + ((u >> 16) & 1u)) >> 16;   // RNE
    return (unsigned short)u;
}
// packed f32 pair -> bf16x2 in one u32 (low = a, high = b). Compiler
// intrinsic (no inline asm); memcpy pun (defined behavior, zero-cost).
__device__ __forceinline__ unsigned int pk2(float a, float b) {
    __hip_bfloat162 h = __float22bfloat162_rn(float2{a, b});
    unsigned int r;
    __builtin_memcpy(&r, &h, sizeof(r));
    return r;
}

// ---------------- K0: weight prep (98 blocks) ----------------
// bid<96: Wt[384][64] bf16 (QKV weights, Q scaled). bid==96: bias[384] f32.
// bid==97: Wt2[32][128] bf16 = Wo^T (out-projection weights, n x c layout).
__global__ __launch_bounds__(256) void wprep_kernel(
    const float* __restrict__ Wq, const float* __restrict__ bq,
    const float* __restrict__ Wk, const float* __restrict__ bk,
    const float* __restrict__ Wv, const float* __restrict__ bv,
    const float* __restrict__ Wo,
    unsigned short* __restrict__ Wt, float* __restrict__ bias,
    unsigned short* __restrict__ Wt2)
{
    const int bid = blockIdx.x, tid = threadIdx.x;
    if (bid < 96) {
        const int idx = bid * 256 + tid;         // 0..24575
        const int m = idx >> 13, f = idx & 8191;
        const int h = f >> 11, c = (f >> 5) & 63, d = f & 31;
        const float* W = (m == 0) ? Wq : (m == 1) ? Wk : Wv;
        float v = W[f] * ((m == 0) ? QSCALE_LOG2E : 1.0f);
        Wt[(size_t)(m * 128 + h * 32 + d) * 64 + c] = f2bf(v);
    } else if (bid == 96) {
        for (int idx = tid; idx < 384; idx += 256) {
            int m = idx >> 7, o = idx & 127;
            const float* bs = (m == 0) ? bq : (m == 1) ? bk : bv;
            bias[idx] = bs[o] * ((m == 0) ? QSCALE_LOG2E : 1.0f);
        }
    } else {
        // Wo[c][n] (128x32) -> Wt2[n][c] bf16 (32x128), 4096 elems
        for (int idx = tid; idx < 4096; idx += 256) {
            int n = idx >> 7, c = idx & 127;
            Wt2[idx] = f2bf(Wo[c * 32 + n]);
        }
    }
}

// ---------------- K1: MFMA QKV projection, 64-row tiles ----------------
// grid 1024 (was 512 x 128-row): 64 X-rows per block -> 4 blocks/CU x 4
// waves = 16 waves/CU (was 8) for this store-latency-heavy kernel. Per-wave
// code is the R21-proven kernel with st-tiles 8->4 and staging 8->4.
__global__ __launch_bounds__(256, 4) void qkv_kernel(
    const float* __restrict__ X, const unsigned short* __restrict__ Wt,
    const float* __restrict__ bias,
    unsigned short* __restrict__ Qo, unsigned short* __restrict__ Ko,
    unsigned short* __restrict__ Vo)
{
    __shared__ unsigned int Xs[64 * 36];   // bf16 [64][72] (72 = 64 + 8 pad)

    const int tid  = threadIdx.x;
    const int row0 = blockIdx.x * 64;
    const int w    = tid >> 6, lane = tid & 63;
    const int lq   = lane & 15, lg = lane >> 4;

    {
        const float4* Xg = reinterpret_cast<const float4*>(X + (size_t)row0 * C_);
        #pragma unroll
        for (int k = 0; k < 4; ++k) {
            int f4 = tid + k * 256;          // 0..1023 (64 rows x 16 chunks)
            int r = f4 >> 4, c4 = f4 & 15;
            float4 x = Xg[f4];
            u32x2 p;
            p[0] = pk2(x.x, x.y);
            p[1] = pk2(x.z, x.w);
            *reinterpret_cast<u32x2*>(&Xs[r * 36 + c4 * 2]) = p;
        }
    }
    __syncthreads();

    const int b  = row0 / S_;        // 64 | 512 -> uniform per block
    const int sb = row0 % S_;

    #pragma unroll
    for (int m = 0; m < 3; ++m) {
        const unsigned short* Wtm = Wt + (size_t)(m * 128) * 64;
        const float* bm = bias + m * 128;
        unsigned short* Out = (m == 0) ? Qo : (m == 1) ? Ko : Vo;

        #pragma unroll
        for (int ni = 0; ni < 2; ++ni) {
            const int nt = 2 * w + ni;           // n-tile 0..7
            const int n0 = nt * 16;
            bf16x8 wf0 = *reinterpret_cast<const bf16x8*>(Wtm + (size_t)(n0 + lq) * 64 + lg * 8);
            bf16x8 wf1 = *reinterpret_cast<const bf16x8*>(Wtm + (size_t)(n0 + lq) * 64 + 32 + lg * 8);

            if (m != 2) {
                const int nrow = n0 + 4 * lg;                 // 4 consecutive n
                const int h = nrow >> 5, d0 = nrow & 31;
                f32x4 bv4 = *reinterpret_cast<const f32x4*>(bm + nrow);
                unsigned short* obase = Out + ((size_t)(b * H_ + h) * S_ + sb) * D_ + d0;
                #pragma unroll
                for (int st = 0; st < 4; ++st) {
                    const unsigned int* xr = &Xs[(st * 16 + lq) * 36];
                    bf16x8 xf0 = *reinterpret_cast<const bf16x8*>(xr + lg * 4);
                    bf16x8 xf1 = *reinterpret_cast<const bf16x8*>(xr + 16 + lg * 4);
                    f32x4 acc;
                    acc[0] = 0.f; acc[1] = 0.f; acc[2] = 0.f; acc[3] = 0.f;
                    acc = __builtin_amdgcn_mfma_f32_16x16x32_bf16(wf0, xf0, acc, 0, 0, 0);
                    acc = __builtin_amdgcn_mfma_f32_16x16x32_bf16(wf1, xf1, acc, 0, 0, 0);
                    u32x2 cc;
                    cc[0] = pk2(acc[0] + bv4[0], acc[1] + bv4[1]);
                    cc[1] = pk2(acc[2] + bv4[2], acc[3] + bv4[3]);
                    *reinterpret_cast<u32x2*>(obase + (size_t)(st * 16 + lq) * D_) = cc;
                }
            } else {
                const int ncol = n0 + lq;                     // one n (= h,d) per lane
                const int h = ncol >> 5, d = ncol & 31;
                const float bsc = bm[ncol];
                unsigned short* obase = Out + ((size_t)(b * H_ + h) * S_) * D_
                                      + (size_t)d * S_ + sb + 4 * lg;
                #pragma unroll
                for (int st = 0; st < 4; ++st) {
                    const unsigned int* xr = &Xs[(st * 16 + lq) * 36];
                    bf16x8 xf0 = *reinterpret_cast<const bf16x8*>(xr + lg * 4);
                    bf16x8 xf1 = *reinterpret_cast<const bf16x8*>(xr + 16 + lg * 4);
                    f32x4 acc;
                    acc[0] = 0.f; acc[1] = 0.f; acc[2] = 0.f; acc[3] = 0.f;
                    acc = __builtin_amdgcn_mfma_f32_16x16x32_bf16(xf0, wf0, acc, 0, 0, 0);
                    acc = __builtin_amdgcn_mfma_f32_16x16x32_bf16(xf1, wf1, acc, 0, 0, 0);
                    u32x2 cc;
                    cc[0] = pk2(acc[0] + bsc, acc[1] + bsc);
                    cc[1] = pk2(acc[2] + bsc, acc[3] + bsc);
                    *reinterpret_cast<u32x2*>(obase + st * 16) = cc;
                }
            }
        }
    }
}

// ---------------- K2: MFMA attention (R21 form, unroll 2 -> 4) ----------
__global__ __launch_bounds__(1024) void attn_kernel(
    const unsigned short* __restrict__ Qb, const unsigned short* __restrict__ Kb,
    const unsigned short* __restrict__ Vtb, unsigned short* __restrict__ ctx)
{
    __shared__ unsigned short Ks[512 * 40];   // 40960 B
    __shared__ unsigned short Vs[32 * 524];   // 33536 B (stride 524 = anti-conflict)

    const int bh  = blockIdx.x;
    const int b   = bh >> 2, h = bh & 3;
    const int tid = threadIdx.x;
    const int w   = tid >> 6, lane = tid & 63;
    const int lq  = lane & 15, lg = lane >> 4;

    const unsigned short* Qp = Qb  + (size_t)bh * (S_ * D_);
    const unsigned short* Kp = Kb  + (size_t)bh * (S_ * D_);
    const unsigned short* Vp = Vtb + (size_t)bh * (S_ * D_);

    #pragma unroll
    for (int it = 0; it < 2; ++it) {
        int idx = it * 1024 + tid;            // 0..2047
        int r = idx >> 2, q4 = idx & 3;
        u16x8 x = *reinterpret_cast<const u16x8*>(Kp + r * 32 + q4 * 8);
        *reinterpret_cast<u16x8*>(&Ks[r * 40 + q4 * 8]) = x;
    }
    #pragma unroll
    for (int it = 0; it < 2; ++it) {
        int idx = it * 1024 + tid;            // 0..2047
        int r = idx >> 6, c = idx & 63;
        u16x8 x = *reinterpret_cast<const u16x8*>(Vp + r * 512 + c * 8);
        u16x4 lo; lo[0] = x[0]; lo[1] = x[1]; lo[2] = x[2]; lo[3] = x[3];
        u16x4 hi; hi[0] = x[4]; hi[1] = x[5]; hi[2] = x[6]; hi[3] = x[7];
        *reinterpret_cast<u16x4*>(&Vs[r * 524 + c * 8])     = lo;
        *reinterpret_cast<u16x4*>(&Vs[r * 524 + c * 8 + 4]) = hi;
    }
    __syncthreads();

    const int q0 = w * 32;

    bf16x8 qf[2];
    #pragma unroll
    for (int qi = 0; qi < 2; ++qi)
        qf[qi] = *reinterpret_cast<const bf16x8*>(
            Qp + (size_t)(q0 + qi * 16 + lq) * D_ + lg * 8);

    u32x4 onesu;
    onesu[0] = 0x3F803F80u; onesu[1] = 0x3F803F80u;
    onesu[2] = 0x3F803F80u; onesu[3] = 0x3F803F80u;
    const bf16x8 vones = __builtin_bit_cast(bf16x8, onesu);

    f32x4 acc[2][2];
    f32x4 lacc[2];
    #pragma unroll
    for (int qi = 0; qi < 2; ++qi) {
        lacc[qi][0] = 0.f; lacc[qi][1] = 0.f; lacc[qi][2] = 0.f; lacc[qi][3] = 0.f;
        #pragma unroll
        for (int dt = 0; dt < 2; ++dt) {
            acc[qi][dt][0] = 0.f; acc[qi][dt][1] = 0.f;
            acc[qi][dt][2] = 0.f; acc[qi][dt][3] = 0.f;
        }
    }

    const unsigned short* kl0 = &Ks[lq * 40 + lg * 8];
    const unsigned short* kl1 = &Ks[(16 + lq) * 40 + lg * 8];
    const unsigned short* vl0 = &Vs[lq * 524 + 4 * lg];          // d=lq
    const unsigned short* vl1 = &Vs[(16 + lq) * 524 + 4 * lg];   // d=16+lq

    #pragma unroll 4
    for (int tc = 0; tc < 16; ++tc) {
        const int t0 = tc * 32;
        bf16x8 k0 = *reinterpret_cast<const bf16x8*>(kl0 + t0 * 40);
        bf16x8 k1 = *reinterpret_cast<const bf16x8*>(kl1 + t0 * 40);

        u32x2 va = *reinterpret_cast<const u32x2*>(vl0 + t0);
        u32x2 vb = *reinterpret_cast<const u32x2*>(vl0 + t0 + 16);
        u32x2 vc = *reinterpret_cast<const u32x2*>(vl1 + t0);
        u32x2 vd = *reinterpret_cast<const u32x2*>(vl1 + t0 + 16);
        u32x4 v0u; v0u[0] = va[0]; v0u[1] = va[1]; v0u[2] = vb[0]; v0u[3] = vb[1];
        u32x4 v1u; v1u[0] = vc[0]; v1u[1] = vc[1]; v1u[2] = vd[0]; v1u[3] = vd[1];
        bf16x8 v0 = __builtin_bit_cast(bf16x8, v0u);
        bf16x8 v1 = __builtin_bit_cast(bf16x8, v1u);

        __builtin_amdgcn_s_setprio(1);
        #pragma unroll
        for (int qi = 0; qi < 2; ++qi) {
            f32x4 z; z[0] = 0.f; z[1] = 0.f; z[2] = 0.f; z[3] = 0.f;
            f32x4 s0 = __builtin_amdgcn_mfma_f32_16x16x32_bf16(k0, qf[qi], z, 0, 0, 0);
            f32x4 s1 = __builtin_amdgcn_mfma_f32_16x16x32_bf16(k1, qf[qi], z, 0, 0, 0);
            float pa = __builtin_amdgcn_exp2f(s0[0]);
            float pb = __builtin_amdgcn_exp2f(s0[1]);
            float pc = __builtin_amdgcn_exp2f(s0[2]);
            float pd = __builtin_amdgcn_exp2f(s0[3]);
            float pe = __builtin_amdgcn_exp2f(s1[0]);
            float pf = __builtin_amdgcn_exp2f(s1[1]);
            float pg = __builtin_amdgcn_exp2f(s1[2]);
            float ph = __builtin_amdgcn_exp2f(s1[3]);
            u32x4 pu;
            pu[0] = pk2(pa, pb);
            pu[1] = pk2(pc, pd);
            pu[2] = pk2(pe, pf);
            pu[3] = pk2(pg, ph);
            bf16x8 pfr = __builtin_bit_cast(bf16x8, pu);
            acc[qi][0] = __builtin_amdgcn_mfma_f32_16x16x32_bf16(v0, pfr, acc[qi][0], 0, 0, 0);
            acc[qi][1] = __builtin_amdgcn_mfma_f32_16x16x32_bf16(v1, pfr, acc[qi][1], 0, 0, 0);
            lacc[qi]   = __builtin_amdgcn_mfma_f32_16x16x32_bf16(vones, pfr, lacc[qi], 0, 0, 0);
        }
        __builtin_amdgcn_s_setprio(0);
    }

    #pragma unroll
    for (int qi = 0; qi < 2; ++qi) {
        const float inv = 1.0f / lacc[qi][0];   // every lane: lsum for q=lq
        const int qg = q0 + qi * 16 + lq;
        #pragma unroll
        for (int dt = 0; dt < 2; ++dt) {
            u32x2 c;
            c[0] = pk2(acc[qi][dt][0] * inv, acc[qi][dt][1] * inv);
            c[1] = pk2(acc[qi][dt][2] * inv, acc[qi][dt][3] * inv);
            unsigned short* cp = ctx + ((size_t)(b * S_ + qg)) * (H_ * D_)
                               + h * D_ + dt * 16 + lg * 4;
            *reinterpret_cast<u32x2*>(cp) = c;
        }
    }
}

// ---------------- K3: MFMA output projection (R23 proven) ----------------
__global__ __launch_bounds__(256, 4) void out_kernel(
    const unsigned short* __restrict__ ctx, const unsigned short* __restrict__ Wt2,
    const float* __restrict__ bo, float* __restrict__ out)
{
    __shared__ unsigned int Cs[128 * 68];   // bf16 [128][136] (136 = 128 + 8 pad)

    const int tid  = threadIdx.x;
    const int row0 = blockIdx.x * 128;
    const int w    = tid >> 6, lane = tid & 63;
    const int lq   = lane & 15, lg = lane >> 4;

    #pragma unroll
    for (int k = 0; k < 8; ++k) {
        int f4 = tid + k * 256;               // 0..2047
        int r = f4 >> 4, c4 = f4 & 15;
        u16x8 x = *reinterpret_cast<const u16x8*>(ctx + (size_t)(row0 + r) * 128 + c4 * 8);
        *reinterpret_cast<u16x8*>(&Cs[r * 68 + c4 * 4]) = x;
    }
    __syncthreads();

    bf16x8 wf[2][4];
    #pragma unroll
    for (int nt = 0; nt < 2; ++nt)
        #pragma unroll
        for (int kk = 0; kk < 4; ++kk)
            wf[nt][kk] = *reinterpret_cast<const bf16x8*>(
                Wt2 + (size_t)(nt * 16 + lq) * 128 + kk * 32 + lg * 8);

    const int nrow = 4 * lg;
    f32x4 bv0, bv1;
    #pragma unroll
    for (int j = 0; j < 4; ++j) { bv0[j] = bo[nrow + j]; bv1[j] = bo[16 + nrow + j]; }

    #pragma unroll
    for (int i = 0; i < 2; ++i) {
        const int st = w * 2 + i;
        const unsigned int* xr = &Cs[(st * 16 + lq) * 68];
        f32x4 a0, a1;
        a0[0] = 0.f; a0[1] = 0.f; a0[2] = 0.f; a0[3] = 0.f;
        a1[0] = 0.f; a1[1] = 0.f; a1[2] = 0.f; a1[3] = 0.f;
        #pragma unroll
        for (int kk = 0; kk < 4; ++kk) {
            bf16x8 xf = *reinterpret_cast<const bf16x8*>(xr + kk * 16 + lg * 4);
            a0 = __builtin_amdgcn_mfma_f32_16x16x32_bf16(wf[0][kk], xf, a0, 0, 0, 0);
            a1 = __builtin_amdgcn_mfma_f32_16x16x32_bf16(wf[1][kk], xf, a1, 0, 0, 0);
        }
        float* op = out + (size_t)(row0 + st * 16 + lq) * 32;
        f32x4 r0, r1;
        #pragma unroll
        for (int j = 0; j < 4; ++j) { r0[j] = a0[j] + bv0[j]; r1[j] = a1[j] + bv1[j]; }
        *reinterpret_cast<f32x4*>(op + nrow)      = r0;
        *reinterpret_cast<f32x4*>(op + 16 + nrow) = r1;
    }
}

extern "C" void kernel_launch(void* const* d_in, const int* in_sizes, int n_in,
                              void* d_out, int out_size, void* d_ws, size_t ws_size,
                              hipStream_t stream) {
    const float* X  = (const float*)d_in[0];
    const float* Wq = (const float*)d_in[1];
    const float* bq = (const float*)d_in[2];
    const float* Wk = (const float*)d_in[3];
    const float* bk = (const float*)d_in[4];
    const float* Wv = (const float*)d_in[5];
    const float* bv = (const float*)d_in[6];
    const float* Wo = (const float*)d_in[7];
    const float* bo = (const float*)d_in[8];
    float* out = (float*)d_out;

    const size_t per = (size_t)B_ * H_ * S_ * D_;            // 8388608
    const size_t need = 4 * per * sizeof(unsigned short)
                      + 24576 * 2 + 384 * 4 + 4096 * 2;
    if (ws_size < need) return;

    unsigned short* Qb   = (unsigned short*)d_ws;
    unsigned short* Kb   = Qb + per;
    unsigned short* Vtb  = Kb + per;
    unsigned short* ctx  = Vtb + per;
    unsigned short* Wt   = ctx + per;
    float*          bias = (float*)(Wt + 24576);
    unsigned short* Wt2  = (unsigned short*)(bias + 384);

    wprep_kernel<<<98, 256, 0, stream>>>(Wq, bq, Wk, bk, Wv, bv, Wo, Wt, bias, Wt2);
    qkv_kernel<<<1024, 256, 0, stream>>>(X, Wt, bias, Qb, Kb, Vtb);
    attn_kernel<<<512, 1024, 0, stream>>>(Qb, Kb, Vtb, ctx);
    out_kernel<<<512, 256, 0, stream>>>(ctx, Wt2, bo, out);
}

// Round 25
// 62.355 us; speedup vs baseline: 1.0229x; 1.0229x over previous
//
#include <hip/hip_runtime.h>
#include <hip/hip_bf16.h>

// Problem constants
#define B_ 128
#define S_ 512
#define C_ 64
#define H_ 4
#define D_ 32
// SCALE * log2(e): folded into Wq/bq at prep so softmax uses raw exp2
#define QSCALE_LOG2E 0.25505654249765306f

typedef __attribute__((ext_vector_type(8))) short bf16x8;
typedef __attribute__((ext_vector_type(8))) unsigned short u16x8;
typedef __attribute__((ext_vector_type(4))) unsigned short u16x4;
typedef __attribute__((ext_vector_type(4))) float f32x4;
typedef __attribute__((ext_vector_type(4))) unsigned int u32x4;
typedef __attribute__((ext_vector_type(2))) unsigned int u32x2;

__device__ __forceinline__ unsigned short f2bf(float f) {
    unsigned int u = __float_as_uint(f);
    u = (u + 0x7FFFu + ((u >> 16) & 1u)) >> 16;   // RNE
    return (unsigned short)u;
}
// packed f32 pair -> bf16x2 in one u32 (low = a, high = b). Compiler
// intrinsic (no inline asm); memcpy pun (defined behavior, zero-cost).
__device__ __forceinline__ unsigned int pk2(float a, float b) {
    __hip_bfloat162 h = __float22bfloat162_rn(float2{a, b});
    unsigned int r;
    __builtin_memcpy(&r, &h, sizeof(r));
    return r;
}

// ---------------- K0: weight prep (98 blocks) ----------------
// bid<96: Wt[384][64] bf16 (QKV weights, Q scaled). bid==96: bias[384] f32.
// bid==97: Wt2[32][128] bf16 = Wo^T (out-projection weights, n x c layout).
__global__ __launch_bounds__(256) void wprep_kernel(
    const float* __restrict__ Wq, const float* __restrict__ bq,
    const float* __restrict__ Wk, const float* __restrict__ bk,
    const float* __restrict__ Wv, const float* __restrict__ bv,
    const float* __restrict__ Wo,
    unsigned short* __restrict__ Wt, float* __restrict__ bias,
    unsigned short* __restrict__ Wt2)
{
    const int bid = blockIdx.x, tid = threadIdx.x;
    if (bid < 96) {
        const int idx = bid * 256 + tid;         // 0..24575
        const int m = idx >> 13, f = idx & 8191;
        const int h = f >> 11, c = (f >> 5) & 63, d = f & 31;
        const float* W = (m == 0) ? Wq : (m == 1) ? Wk : Wv;
        float v = W[f] * ((m == 0) ? QSCALE_LOG2E : 1.0f);
        Wt[(size_t)(m * 128 + h * 32 + d) * 64 + c] = f2bf(v);
    } else if (bid == 96) {
        for (int idx = tid; idx < 384; idx += 256) {
            int m = idx >> 7, o = idx & 127;
            const float* bs = (m == 0) ? bq : (m == 1) ? bk : bv;
            bias[idx] = bs[o] * ((m == 0) ? QSCALE_LOG2E : 1.0f);
        }
    } else {
        // Wo[c][n] (128x32) -> Wt2[n][c] bf16 (32x128), 4096 elems
        for (int idx = tid; idx < 4096; idx += 256) {
            int n = idx >> 7, c = idx & 127;
            Wt2[idx] = f2bf(Wo[c * 32 + n]);
        }
    }
}

// ---------------- K1: MFMA QKV projection, X staged ONCE (R21 proven) ------
__global__ __launch_bounds__(256, 4) void qkv_kernel(
    const float* __restrict__ X, const unsigned short* __restrict__ Wt,
    const float* __restrict__ bias,
    unsigned short* __restrict__ Qo, unsigned short* __restrict__ Ko,
    unsigned short* __restrict__ Vo)
{
    __shared__ unsigned int Xs[128 * 36];   // bf16 [128][72] (72 = 64 + 8 pad)

    const int tid  = threadIdx.x;
    const int row0 = blockIdx.x * 128;
    const int w    = tid >> 6, lane = tid & 63;
    const int lq   = lane & 15, lg = lane >> 4;

    {
        const float4* Xg = reinterpret_cast<const float4*>(X + (size_t)row0 * C_);
        #pragma unroll
        for (int k = 0; k < 8; ++k) {
            int f4 = tid + k * 256;
            int r = f4 >> 4, c4 = f4 & 15;
            float4 x = Xg[f4];
            u32x2 p;
            p[0] = pk2(x.x, x.y);
            p[1] = pk2(x.z, x.w);
            *reinterpret_cast<u32x2*>(&Xs[r * 36 + c4 * 2]) = p;
        }
    }
    __syncthreads();

    const int b  = row0 / S_;
    const int sb = row0 % S_;

    #pragma unroll
    for (int m = 0; m < 3; ++m) {
        const unsigned short* Wtm = Wt + (size_t)(m * 128) * 64;
        const float* bm = bias + m * 128;
        unsigned short* Out = (m == 0) ? Qo : (m == 1) ? Ko : Vo;

        #pragma unroll
        for (int ni = 0; ni < 2; ++ni) {
            const int nt = 2 * w + ni;           // n-tile 0..7
            const int n0 = nt * 16;
            bf16x8 wf0 = *reinterpret_cast<const bf16x8*>(Wtm + (size_t)(n0 + lq) * 64 + lg * 8);
            bf16x8 wf1 = *reinterpret_cast<const bf16x8*>(Wtm + (size_t)(n0 + lq) * 64 + 32 + lg * 8);

            if (m != 2) {
                const int nrow = n0 + 4 * lg;                 // 4 consecutive n
                const int h = nrow >> 5, d0 = nrow & 31;
                f32x4 bv4 = *reinterpret_cast<const f32x4*>(bm + nrow);
                unsigned short* obase = Out + ((size_t)(b * H_ + h) * S_ + sb) * D_ + d0;
                #pragma unroll
                for (int st = 0; st < 8; ++st) {
                    const unsigned int* xr = &Xs[(st * 16 + lq) * 36];
                    bf16x8 xf0 = *reinterpret_cast<const bf16x8*>(xr + lg * 4);
                    bf16x8 xf1 = *reinterpret_cast<const bf16x8*>(xr + 16 + lg * 4);
                    f32x4 acc;
                    acc[0] = 0.f; acc[1] = 0.f; acc[2] = 0.f; acc[3] = 0.f;
                    acc = __builtin_amdgcn_mfma_f32_16x16x32_bf16(wf0, xf0, acc, 0, 0, 0);
                    acc = __builtin_amdgcn_mfma_f32_16x16x32_bf16(wf1, xf1, acc, 0, 0, 0);
                    u32x2 cc;
                    cc[0] = pk2(acc[0] + bv4[0], acc[1] + bv4[1]);
                    cc[1] = pk2(acc[2] + bv4[2], acc[3] + bv4[3]);
                    *reinterpret_cast<u32x2*>(obase + (size_t)(st * 16 + lq) * D_) = cc;
                }
            } else {
                const int ncol = n0 + lq;                     // one n (= h,d) per lane
                const int h = ncol >> 5, d = ncol & 31;
                const float bsc = bm[ncol];
                unsigned short* obase = Out + ((size_t)(b * H_ + h) * S_) * D_
                                      + (size_t)d * S_ + sb + 4 * lg;
                #pragma unroll
                for (int st = 0; st < 8; ++st) {
                    const unsigned int* xr = &Xs[(st * 16 + lq) * 36];
                    bf16x8 xf0 = *reinterpret_cast<const bf16x8*>(xr + lg * 4);
                    bf16x8 xf1 = *reinterpret_cast<const bf16x8*>(xr + 16 + lg * 4);
                    f32x4 acc;
                    acc[0] = 0.f; acc[1] = 0.f; acc[2] = 0.f; acc[3] = 0.f;
                    acc = __builtin_amdgcn_mfma_f32_16x16x32_bf16(xf0, wf0, acc, 0, 0, 0);
                    acc = __builtin_amdgcn_mfma_f32_16x16x32_bf16(xf1, wf1, acc, 0, 0, 0);
                    u32x2 cc;
                    cc[0] = pk2(acc[0] + bsc, acc[1] + bsc);
                    cc[1] = pk2(acc[2] + bsc, acc[3] + bsc);
                    *reinterpret_cast<u32x2*>(obase + st * 16) = cc;
                }
            }
        }
    }
}

// ---------------- K2: MFMA attention (R21/R23 frozen form) ----------
__global__ __launch_bounds__(1024) void attn_kernel(
    const unsigned short* __restrict__ Qb, const unsigned short* __restrict__ Kb,
    const unsigned short* __restrict__ Vtb, unsigned short* __restrict__ ctx)
{
    __shared__ unsigned short Ks[512 * 40];   // 40960 B
    __shared__ unsigned short Vs[32 * 524];   // 33536 B (stride 524 = anti-conflict)

    const int bh  = blockIdx.x;
    const int b   = bh >> 2, h = bh & 3;
    const int tid = threadIdx.x;
    const int w   = tid >> 6, lane = tid & 63;
    const int lq  = lane & 15, lg = lane >> 4;

    const unsigned short* Qp = Qb  + (size_t)bh * (S_ * D_);
    const unsigned short* Kp = Kb  + (size_t)bh * (S_ * D_);
    const unsigned short* Vp = Vtb + (size_t)bh * (S_ * D_);

    #pragma unroll
    for (int it = 0; it < 2; ++it) {
        int idx = it * 1024 + tid;            // 0..2047
        int r = idx >> 2, q4 = idx & 3;
        u16x8 x = *reinterpret_cast<const u16x8*>(Kp + r * 32 + q4 * 8);
        *reinterpret_cast<u16x8*>(&Ks[r * 40 + q4 * 8]) = x;
    }
    #pragma unroll
    for (int it = 0; it < 2; ++it) {
        int idx = it * 1024 + tid;            // 0..2047
        int r = idx >> 6, c = idx & 63;
        u16x8 x = *reinterpret_cast<const u16x8*>(Vp + r * 512 + c * 8);
        u16x4 lo; lo[0] = x[0]; lo[1] = x[1]; lo[2] = x[2]; lo[3] = x[3];
        u16x4 hi; hi[0] = x[4]; hi[1] = x[5]; hi[2] = x[6]; hi[3] = x[7];
        *reinterpret_cast<u16x4*>(&Vs[r * 524 + c * 8])     = lo;
        *reinterpret_cast<u16x4*>(&Vs[r * 524 + c * 8 + 4]) = hi;
    }
    __syncthreads();

    const int q0 = w * 32;

    bf16x8 qf[2];
    #pragma unroll
    for (int qi = 0; qi < 2; ++qi)
        qf[qi] = *reinterpret_cast<const bf16x8*>(
            Qp + (size_t)(q0 + qi * 16 + lq) * D_ + lg * 8);

    u32x4 onesu;
    onesu[0] = 0x3F803F80u; onesu[1] = 0x3F803F80u;
    onesu[2] = 0x3F803F80u; onesu[3] = 0x3F803F80u;
    const bf16x8 vones = __builtin_bit_cast(bf16x8, onesu);

    f32x4 acc[2][2];
    f32x4 lacc[2];
    #pragma unroll
    for (int qi = 0; qi < 2; ++qi) {
        lacc[qi][0] = 0.f; lacc[qi][1] = 0.f; lacc[qi][2] = 0.f; lacc[qi][3] = 0.f;
        #pragma unroll
        for (int dt = 0; dt < 2; ++dt) {
            acc[qi][dt][0] = 0.f; acc[qi][dt][1] = 0.f;
            acc[qi][dt][2] = 0.f; acc[qi][dt][3] = 0.f;
        }
    }

    const unsigned short* kl0 = &Ks[lq * 40 + lg * 8];
    const unsigned short* kl1 = &Ks[(16 + lq) * 40 + lg * 8];
    const unsigned short* vl0 = &Vs[lq * 524 + 4 * lg];          // d=lq
    const unsigned short* vl1 = &Vs[(16 + lq) * 524 + 4 * lg];   // d=16+lq

    #pragma unroll 2
    for (int tc = 0; tc < 16; ++tc) {
        const int t0 = tc * 32;
        bf16x8 k0 = *reinterpret_cast<const bf16x8*>(kl0 + t0 * 40);
        bf16x8 k1 = *reinterpret_cast<const bf16x8*>(kl1 + t0 * 40);

        u32x2 va = *reinterpret_cast<const u32x2*>(vl0 + t0);
        u32x2 vb = *reinterpret_cast<const u32x2*>(vl0 + t0 + 16);
        u32x2 vc = *reinterpret_cast<const u32x2*>(vl1 + t0);
        u32x2 vd = *reinterpret_cast<const u32x2*>(vl1 + t0 + 16);
        u32x4 v0u; v0u[0] = va[0]; v0u[1] = va[1]; v0u[2] = vb[0]; v0u[3] = vb[1];
        u32x4 v1u; v1u[0] = vc[0]; v1u[1] = vc[1]; v1u[2] = vd[0]; v1u[3] = vd[1];
        bf16x8 v0 = __builtin_bit_cast(bf16x8, v0u);
        bf16x8 v1 = __builtin_bit_cast(bf16x8, v1u);

        __builtin_amdgcn_s_setprio(1);
        #pragma unroll
        for (int qi = 0; qi < 2; ++qi) {
            f32x4 z; z[0] = 0.f; z[1] = 0.f; z[2] = 0.f; z[3] = 0.f;
            f32x4 s0 = __builtin_amdgcn_mfma_f32_16x16x32_bf16(k0, qf[qi], z, 0, 0, 0);
            f32x4 s1 = __builtin_amdgcn_mfma_f32_16x16x32_bf16(k1, qf[qi], z, 0, 0, 0);
            float pa = __builtin_amdgcn_exp2f(s0[0]);
            float pb = __builtin_amdgcn_exp2f(s0[1]);
            float pc = __builtin_amdgcn_exp2f(s0[2]);
            float pd = __builtin_amdgcn_exp2f(s0[3]);
            float pe = __builtin_amdgcn_exp2f(s1[0]);
            float pf = __builtin_amdgcn_exp2f(s1[1]);
            float pg = __builtin_amdgcn_exp2f(s1[2]);
            float ph = __builtin_amdgcn_exp2f(s1[3]);
            u32x4 pu;
            pu[0] = pk2(pa, pb);
            pu[1] = pk2(pc, pd);
            pu[2] = pk2(pe, pf);
            pu[3] = pk2(pg, ph);
            bf16x8 pfr = __builtin_bit_cast(bf16x8, pu);
            acc[qi][0] = __builtin_amdgcn_mfma_f32_16x16x32_bf16(v0, pfr, acc[qi][0], 0, 0, 0);
            acc[qi][1] = __builtin_amdgcn_mfma_f32_16x16x32_bf16(v1, pfr, acc[qi][1], 0, 0, 0);
            lacc[qi]   = __builtin_amdgcn_mfma_f32_16x16x32_bf16(vones, pfr, lacc[qi], 0, 0, 0);
        }
        __builtin_amdgcn_s_setprio(0);
    }

    #pragma unroll
    for (int qi = 0; qi < 2; ++qi) {
        const float inv = 1.0f / lacc[qi][0];   // every lane: lsum for q=lq
        const int qg = q0 + qi * 16 + lq;
        #pragma unroll
        for (int dt = 0; dt < 2; ++dt) {
            u32x2 c;
            c[0] = pk2(acc[qi][dt][0] * inv, acc[qi][dt][1] * inv);
            c[1] = pk2(acc[qi][dt][2] * inv, acc[qi][dt][3] * inv);
            unsigned short* cp = ctx + ((size_t)(b * S_ + qg)) * (H_ * D_)
                               + h * D_ + dt * 16 + lg * 4;
            *reinterpret_cast<u32x2*>(cp) = c;
        }
    }
}

// ---------------- K3: MFMA output projection (R23 proven) ----------------
__global__ __launch_bounds__(256, 4) void out_kernel(
    const unsigned short* __restrict__ ctx, const unsigned short* __restrict__ Wt2,
    const float* __restrict__ bo, float* __restrict__ out)
{
    __shared__ unsigned int Cs[128 * 68];   // bf16 [128][136] (136 = 128 + 8 pad)

    const int tid  = threadIdx.x;
    const int row0 = blockIdx.x * 128;
    const int w    = tid >> 6, lane = tid & 63;
    const int lq   = lane & 15, lg = lane >> 4;

    #pragma unroll
    for (int k = 0; k < 8; ++k) {
        int f4 = tid + k * 256;               // 0..2047
        int r = f4 >> 4, c4 = f4 & 15;
        u16x8 x = *reinterpret_cast<const u16x8*>(ctx + (size_t)(row0 + r) * 128 + c4 * 8);
        *reinterpret_cast<u16x8*>(&Cs[r * 68 + c4 * 4]) = x;
    }
    __syncthreads();

    bf16x8 wf[2][4];
    #pragma unroll
    for (int nt = 0; nt < 2; ++nt)
        #pragma unroll
        for (int kk = 0; kk < 4; ++kk)
            wf[nt][kk] = *reinterpret_cast<const bf16x8*>(
                Wt2 + (size_t)(nt * 16 + lq) * 128 + kk * 32 + lg * 8);

    const int nrow = 4 * lg;
    f32x4 bv0, bv1;
    #pragma unroll
    for (int j = 0; j < 4; ++j) { bv0[j] = bo[nrow + j]; bv1[j] = bo[16 + nrow + j]; }

    #pragma unroll
    for (int i = 0; i < 2; ++i) {
        const int st = w * 2 + i;
        const unsigned int* xr = &Cs[(st * 16 + lq) * 68];
        f32x4 a0, a1;
        a0[0] = 0.f; a0[1] = 0.f; a0[2] = 0.f; a0[3] = 0.f;
        a1[0] = 0.f; a1[1] = 0.f; a1[2] = 0.f; a1[3] = 0.f;
        #pragma unroll
        for (int kk = 0; kk < 4; ++kk) {
            bf16x8 xf = *reinterpret_cast<const bf16x8*>(xr + kk * 16 + lg * 4);
            a0 = __builtin_amdgcn_mfma_f32_16x16x32_bf16(wf[0][kk], xf, a0, 0, 0, 0);
            a1 = __builtin_amdgcn_mfma_f32_16x16x32_bf16(wf[1][kk], xf, a1, 0, 0, 0);
        }
        float* op = out + (size_t)(row0 + st * 16 + lq) * 32;
        f32x4 r0, r1;
        #pragma unroll
        for (int j = 0; j < 4; ++j) { r0[j] = a0[j] + bv0[j]; r1[j] = a1[j] + bv1[j]; }
        *reinterpret_cast<f32x4*>(op + nrow)      = r0;
        *reinterpret_cast<f32x4*>(op + 16 + nrow) = r1;
    }
}

extern "C" void kernel_launch(void* const* d_in, const int* in_sizes, int n_in,
                              void* d_out, int out_size, void* d_ws, size_t ws_size,
                              hipStream_t stream) {
    const float* X  = (const float*)d_in[0];
    const float* Wq = (const float*)d_in[1];
    const float* bq = (const float*)d_in[2];
    const float* Wk = (const float*)d_in[3];
    const float* bk = (const float*)d_in[4];
    const float* Wv = (const float*)d_in[5];
    const float* bv = (const float*)d_in[6];
    const float* Wo = (const float*)d_in[7];
    const float* bo = (const float*)d_in[8];
    float* out = (float*)d_out;

    const size_t per = (size_t)B_ * H_ * S_ * D_;            // 8388608
    const size_t need = 4 * per * sizeof(unsigned short)
                      + 24576 * 2 + 384 * 4 + 4096 * 2;
    if (ws_size < need) return;

    unsigned short* Qb   = (unsigned short*)d_ws;
    unsigned short* Kb   = Qb + per;
    unsigned short* Vtb  = Kb + per;
    unsigned short* ctx  = Vtb + per;
    unsigned short* Wt   = ctx + per;
    float*          bias = (float*)(Wt + 24576);
    unsigned short* Wt2  = (unsigned short*)(bias + 384);

    wprep_kernel<<<98, 256, 0, stream>>>(Wq, bq, Wk, bk, Wv, bv, Wo, Wt, bias, Wt2);
    qkv_kernel<<<512, 256, 0, stream>>>(X, Wt, bias, Qb, Kb, Vtb);
    attn_kernel<<<512, 1024, 0, stream>>>(Qb, Kb, Vtb, ctx);
    out_kernel<<<512, 256, 0, stream>>>(ctx, Wt2, bo, out);
}